// Round 14
// baseline (26.840 us; speedup 1.0000x reference)
//
#include <hip/hip_runtime.h>

#define IMG_H 512
#define IMG_W 512
#define NIMG  32
#define RPW   4                      // output rows per wave
#define NWAVE 4                      // waves per block
#define ROWS_PER_BLOCK (RPW * NWAVE) // 16
#define STRIPS (IMG_H / ROWS_PER_BLOCK) // 32 strips per image
#define NBLK (NIMG * STRIPS)         // 1024 blocks

__device__ __forceinline__ float sh_up(float v, int lane) {
    float t = __shfl_up(v, 1, 64);
    return lane == 0 ? 0.f : t;
}
__device__ __forceinline__ float sh_dn(float v, int lane) {
    float t = __shfl_down(v, 1, 64);
    return lane == 63 ? 0.f : t;
}

// load one row's 8 columns for this lane (zeros outside the image)
__device__ __forceinline__ void rowvals(const float* __restrict__ p, int y, float* x) {
    if ((unsigned)y < (unsigned)IMG_H) {
        const float4* q = (const float4*)(p + (size_t)y * IMG_W);
        float4 a = q[0], b = q[1];
        x[0] = a.x; x[1] = a.y; x[2] = a.z; x[3] = a.w;
        x[4] = b.x; x[5] = b.y; x[6] = b.z; x[7] = b.w;
    } else {
        #pragma unroll
        for (int k = 0; k < 8; ++k) x[k] = 0.f;
    }
}

__device__ __forceinline__ void accrow(const float* x1, const float* x2,
        float* s1, float* s2, float* s11, float* s22, float* s12) {
    #pragma unroll
    for (int k = 0; k < 8; ++k) {
        s1[k] += x1[k]; s2[k] += x2[k];
        s11[k] = fmaf(x1[k], x1[k], s11[k]);
        s22[k] = fmaf(x2[k], x2[k], s22[k]);
        s12[k] = fmaf(x1[k], x2[k], s12[k]);
    }
}
__device__ __forceinline__ void subrow(const float* x1, const float* x2,
        float* s1, float* s2, float* s11, float* s22, float* s12) {
    #pragma unroll
    for (int k = 0; k < 8; ++k) {
        s1[k] -= x1[k]; s2[k] -= x2[k];
        s11[k] = fmaf(-x1[k], x1[k], s11[k]);
        s22[k] = fmaf(-x2[k], x2[k], s22[k]);
        s12[k] = fmaf(-x1[k], x2[k], s12[k]);
    }
}

// horizontal 7-box-sum: v[0..7] = this lane's 8 column values (vertical sums),
// halo via lane+-1 shuffles, sliding-window in registers.
__device__ __forceinline__ void hbox(const float* v, float* h, int lane) {
    float l5 = sh_up(v[5], lane), l6 = sh_up(v[6], lane), l7 = sh_up(v[7], lane);
    float r0 = sh_dn(v[0], lane), r1 = sh_dn(v[1], lane), r2 = sh_dn(v[2], lane);
    h[0] = ((l5 + l6) + (l7 + v[0])) + ((v[1] + v[2]) + v[3]);
    h[1] = h[0] - l5   + v[4];
    h[2] = h[1] - l6   + v[5];
    h[3] = h[2] - l7   + v[6];
    h[4] = h[3] - v[0] + v[7];
    h[5] = h[4] - v[1] + r0;
    h[6] = h[5] - v[2] + r1;
    h[7] = h[6] - v[3] + r2;
}

// one output row: horizontal sums + SSIM formula, returns partial sum
__device__ __forceinline__ float rowssim(const float* s1, const float* s2,
        const float* s11, const float* s22, const float* s12, int lane) {
    constexpr float C1f = 1e-4f;   // (0.01)^2
    constexpr float C2f = 9e-4f;   // (0.03)^2
    float h1[8], h2[8], h11[8], h22[8], h12[8];
    hbox(s1,  h1,  lane);
    hbox(s2,  h2,  lane);
    hbox(s11, h11, lane);
    hbox(s22, h22, lane);
    hbox(s12, h12, lane);
    float acc = 0.f;
    #pragma unroll
    for (int k = 0; k < 8; ++k) {
        const float mu1 = h1[k], mu2 = h2[k];
        const float mu11 = mu1 * mu1, mu22 = mu2 * mu2, mu12 = mu1 * mu2;
        const float sg1  = h11[k] - mu11;
        const float sg2  = h22[k] - mu22;
        const float sg12 = h12[k] - mu12;
        const float num = (2.f * mu12 + C1f) * (2.f * sg12 + C2f);
        const float den = (mu11 + mu22 + C1f) * (sg1 + sg2 + C2f);
        float r = __builtin_amdgcn_rcpf(den);
        r = r * (2.0f - den * r);          // den > 0 always; 1 Newton step
        acc = fmaf(num, r, acc);
    }
    return acc;
}

// waves_per_eu(2,8): VGPR budget 256 (cap law ~512/min, measured rounds
// 1-10) -- enough to hold the full 20-buffer burst payload (~230 live) that
// round 9's 96-VGPR budget serialized. Residency floor 2/SIMD, same as the
// 24.3us baseline, so this A/B isolates ISSUED BYTES (268 -> 168 MB).
extern "C" __global__ void
__attribute__((amdgpu_flat_work_group_size(256, 256), amdgpu_waves_per_eu(2, 8)))
ssim_main(const float* __restrict__ img1, const float* __restrict__ img2,
          float* __restrict__ partials)
{
    const int tid  = threadIdx.x;
    const int lane = tid & 63;
    const int wv   = tid >> 6;

    // XCD-aware swizzle: 1024 blocks, 8 XCDs -> each XCD gets 4 whole images
    const int bid   = blockIdx.x;
    const int xcd   = bid & 7;
    const int idx   = bid >> 3;           // 0..127
    const int img   = xcd * (NIMG / 8) + (idx >> 5);
    const int strip = idx & 31;
    const int wy0   = strip * ROWS_PER_BLOCK + wv * RPW;

    const size_t base = (size_t)img * (IMG_H * IMG_W) + (size_t)(lane << 3);
    const float* p1 = img1 + base;
    const float* p2 = img2 + base;

    // Window rows q0..q9 = wy0-3 .. wy0+6.
    //   out0 = box(q0..q6), out1 = box(q1..q7),
    //   out2 = box(q2..q8), out3 = box(q3..q9).
    // ALL 10 row-pair loads issued upfront into distinct statically-indexed
    // buffers (one burst, single latency exposure). q0..q2 stay register-held
    // for the sliding subtract. 2.5 row-loads/output row vs 4.0 at RPW=2.
    float b0a[8], b0b[8], b1a[8], b1b[8], b2a[8], b2b[8], b3a[8], b3b[8];
    float b4a[8], b4b[8], b5a[8], b5b[8], b6a[8], b6b[8], b7a[8], b7b[8];
    float b8a[8], b8b[8], b9a[8], b9b[8];

    rowvals(p1, wy0 - 3, b0a); rowvals(p2, wy0 - 3, b0b);
    rowvals(p1, wy0 - 2, b1a); rowvals(p2, wy0 - 2, b1b);
    rowvals(p1, wy0 - 1, b2a); rowvals(p2, wy0 - 1, b2b);
    rowvals(p1, wy0 + 0, b3a); rowvals(p2, wy0 + 0, b3b);
    rowvals(p1, wy0 + 1, b4a); rowvals(p2, wy0 + 1, b4b);
    rowvals(p1, wy0 + 2, b5a); rowvals(p2, wy0 + 2, b5b);
    rowvals(p1, wy0 + 3, b6a); rowvals(p2, wy0 + 3, b6b);
    rowvals(p1, wy0 + 4, b7a); rowvals(p2, wy0 + 4, b7b);
    rowvals(p1, wy0 + 5, b8a); rowvals(p2, wy0 + 5, b8b);
    rowvals(p1, wy0 + 6, b9a); rowvals(p2, wy0 + 6, b9b);

    float s1[8], s2[8], s11[8], s22[8], s12[8];
    #pragma unroll
    for (int k = 0; k < 8; ++k) { s1[k] = s2[k] = s11[k] = s22[k] = s12[k] = 0.f; }

    accrow(b0a, b0b, s1, s2, s11, s22, s12);   // +q0 (held)
    accrow(b1a, b1b, s1, s2, s11, s22, s12);   // +q1 (held)
    accrow(b2a, b2b, s1, s2, s11, s22, s12);   // +q2 (held)
    accrow(b3a, b3b, s1, s2, s11, s22, s12);   // +q3
    accrow(b4a, b4b, s1, s2, s11, s22, s12);   // +q4
    accrow(b5a, b5b, s1, s2, s11, s22, s12);   // +q5
    accrow(b6a, b6b, s1, s2, s11, s22, s12);   // +q6  (window q0..q6)

    float acc = rowssim(s1, s2, s11, s22, s12, lane);     // row wy0

    subrow(b0a, b0b, s1, s2, s11, s22, s12);   // -q0
    accrow(b7a, b7b, s1, s2, s11, s22, s12);   // +q7  (window q1..q7)

    acc += rowssim(s1, s2, s11, s22, s12, lane);          // row wy0+1

    subrow(b1a, b1b, s1, s2, s11, s22, s12);   // -q1
    accrow(b8a, b8b, s1, s2, s11, s22, s12);   // +q8  (window q2..q8)

    acc += rowssim(s1, s2, s11, s22, s12, lane);          // row wy0+2

    subrow(b2a, b2b, s1, s2, s11, s22, s12);   // -q2
    accrow(b9a, b9b, s1, s2, s11, s22, s12);   // +q9  (window q3..q9)

    acc += rowssim(s1, s2, s11, s22, s12, lane);          // row wy0+3

    // block reduction: wave shuffle-reduce then LDS across 4 waves
    #pragma unroll
    for (int off = 32; off; off >>= 1) acc += __shfl_down(acc, off, 64);

    __shared__ float red[NWAVE];
    if (lane == 0) red[wv] = acc;
    __syncthreads();
    if (tid == 0) {
        partials[bid] = (red[0] + red[1]) + (red[2] + red[3]);
    }
}

extern "C" __global__ void __launch_bounds__(256)
ssim_final(const float* __restrict__ partials, float* __restrict__ out)
{
    // 256 threads, 4 serial loads each, fixed order -> deterministic
    const int tid  = threadIdx.x;
    const int lane = tid & 63;
    const int wv   = tid >> 6;
    double s = 0.0;
    #pragma unroll
    for (int i = 0; i < NBLK / 256; ++i) s += (double)partials[tid + (i << 8)];
    #pragma unroll
    for (int off = 32; off; off >>= 1) s += __shfl_down(s, off, 64);
    __shared__ double sd[4];
    if (lane == 0) sd[wv] = s;
    __syncthreads();
    if (tid == 0) {
        const double t = (sd[0] + sd[1]) + (sd[2] + sd[3]);
        out[0] = (float)(1.0 - t / ((double)NIMG * IMG_H * IMG_W));
    }
}

extern "C" void kernel_launch(void* const* d_in, const int* in_sizes, int n_in,
                              void* d_out, int out_size, void* d_ws, size_t ws_size,
                              hipStream_t stream) {
    const float* img1 = (const float*)d_in[0];
    const float* img2 = (const float*)d_in[1];
    float* partials = (float*)d_ws;   // NBLK floats

    hipLaunchKernelGGL(ssim_main, dim3(NBLK), dim3(256), 0, stream,
                       img1, img2, partials);
    hipLaunchKernelGGL(ssim_final, dim3(1), dim3(256), 0, stream,
                       partials, (float*)d_out);
}

// Round 15
// 22.506 us; speedup vs baseline: 1.1926x; 1.1926x over previous
//
#include <hip/hip_runtime.h>

#define IMG_H 512
#define IMG_W 512
#define NIMG  32
#define RPW   2                      // output rows per wave
#define NWAVE 4                      // waves per block
#define ROWS_PER_BLOCK (RPW * NWAVE) // 8
#define STRIPS (IMG_H / ROWS_PER_BLOCK) // 64 strips per image
#define NBLK (NIMG * STRIPS)         // 2048 blocks

// Whole-wave lane shifts via DPP (one VALU op, no LDS pipe, no lgkm wait).
//  wave_shr:1 (0x138): lane i <- lane i-1, lane 0 <- 0 (bound_ctrl)
//  wave_shl:1 (0x130): lane i <- lane i+1, lane 63 <- 0 (bound_ctrl)
__device__ __forceinline__ float dpp_up1(float v) {   // == sh_up(v,1) w/ 0-fill
    int r = __builtin_amdgcn_update_dpp(0, __float_as_int(v), 0x138, 0xF, 0xF, true);
    return __int_as_float(r);
}
__device__ __forceinline__ float dpp_dn1(float v) {   // == sh_dn(v,1) w/ 0-fill
    int r = __builtin_amdgcn_update_dpp(0, __float_as_int(v), 0x130, 0xF, 0xF, true);
    return __int_as_float(r);
}

// load one row's 8 columns for this lane (zeros outside the image)
__device__ __forceinline__ void rowvals(const float* __restrict__ p, int y, float* x) {
    if ((unsigned)y < (unsigned)IMG_H) {
        const float4* q = (const float4*)(p + (size_t)y * IMG_W);
        float4 a = q[0], b = q[1];
        x[0] = a.x; x[1] = a.y; x[2] = a.z; x[3] = a.w;
        x[4] = b.x; x[5] = b.y; x[6] = b.z; x[7] = b.w;
    } else {
        #pragma unroll
        for (int k = 0; k < 8; ++k) x[k] = 0.f;
    }
}

__device__ __forceinline__ void accrow(const float* x1, const float* x2,
        float* s1, float* s2, float* s11, float* s22, float* s12) {
    #pragma unroll
    for (int k = 0; k < 8; ++k) {
        s1[k] += x1[k]; s2[k] += x2[k];
        s11[k] = fmaf(x1[k], x1[k], s11[k]);
        s22[k] = fmaf(x2[k], x2[k], s22[k]);
        s12[k] = fmaf(x1[k], x2[k], s12[k]);
    }
}
__device__ __forceinline__ void subrow(const float* x1, const float* x2,
        float* s1, float* s2, float* s11, float* s22, float* s12) {
    #pragma unroll
    for (int k = 0; k < 8; ++k) {
        s1[k] -= x1[k]; s2[k] -= x2[k];
        s11[k] = fmaf(-x1[k], x1[k], s11[k]);
        s22[k] = fmaf(-x2[k], x2[k], s22[k]);
        s12[k] = fmaf(-x1[k], x2[k], s12[k]);
    }
}

// horizontal 7-box-sum: v[0..7] = this lane's 8 column values (vertical sums),
// halo via DPP wave shifts, sliding-window in registers.
__device__ __forceinline__ void hbox(const float* v, float* h) {
    float l5 = dpp_up1(v[5]), l6 = dpp_up1(v[6]), l7 = dpp_up1(v[7]);
    float r0 = dpp_dn1(v[0]), r1 = dpp_dn1(v[1]), r2 = dpp_dn1(v[2]);
    h[0] = ((l5 + l6) + (l7 + v[0])) + ((v[1] + v[2]) + v[3]);
    h[1] = h[0] - l5   + v[4];
    h[2] = h[1] - l6   + v[5];
    h[3] = h[2] - l7   + v[6];
    h[4] = h[3] - v[0] + v[7];
    h[5] = h[4] - v[1] + r0;
    h[6] = h[5] - v[2] + r1;
    h[7] = h[6] - v[3] + r2;
}

// one output row: horizontal sums + SSIM formula, returns partial sum
__device__ __forceinline__ float rowssim(const float* s1, const float* s2,
        const float* s11, const float* s22, const float* s12) {
    constexpr float C1f = 1e-4f;   // (0.01)^2
    constexpr float C2f = 9e-4f;   // (0.03)^2
    float h1[8], h2[8], h11[8], h22[8], h12[8];
    hbox(s1,  h1);
    hbox(s2,  h2);
    hbox(s11, h11);
    hbox(s22, h22);
    hbox(s12, h12);
    float acc = 0.f;
    #pragma unroll
    for (int k = 0; k < 8; ++k) {
        const float mu1 = h1[k], mu2 = h2[k];
        const float mu11 = mu1 * mu1, mu22 = mu2 * mu2, mu12 = mu1 * mu2;
        const float sg1  = h11[k] - mu11;
        const float sg2  = h22[k] - mu22;
        const float sg12 = h12[k] - mu12;
        const float num = (2.f * mu12 + C1f) * (2.f * sg12 + C2f);
        const float den = (mu11 + mu22 + C1f) * (sg1 + sg2 + C2f);
        float r = __builtin_amdgcn_rcpf(den);
        r = r * (2.0f - den * r);          // den > 0 always; 1 Newton step
        acc = fmaf(num, r, acc);
    }
    return acc;
}

extern "C" __global__ void __launch_bounds__(256, 2)
ssim_main(const float* __restrict__ img1, const float* __restrict__ img2,
          float* __restrict__ partials)
{
    const int tid  = threadIdx.x;
    const int lane = tid & 63;
    const int wv   = tid >> 6;

    // XCD-aware swizzle: 2048 blocks, 8 XCDs -> each XCD gets 4 whole images
    const int bid   = blockIdx.x;
    const int xcd   = bid & 7;
    const int idx   = bid >> 3;           // 0..255
    const int img   = xcd * (NIMG / 8) + (idx >> 6);
    const int strip = idx & 63;
    const int wy0   = strip * ROWS_PER_BLOCK + wv * RPW;

    const size_t base = (size_t)img * (IMG_H * IMG_W) + (size_t)(lane << 3);
    const float* p1 = img1 + base;
    const float* p2 = img2 + base;

    // Window rows q0..q7 = wy0-3 .. wy0+4.
    //   output row wy0   = box over q0..q6
    //   output row wy0+1 = box over q1..q7
    // ALL 8 row-pair loads issued upfront into distinct statically-indexed
    // buffers -> one global_load burst, single latency exposure per wave.
    float b0a[8], b0b[8], b1a[8], b1b[8], b2a[8], b2b[8], b3a[8], b3b[8];
    float b4a[8], b4b[8], b5a[8], b5b[8], b6a[8], b6b[8], b7a[8], b7b[8];

    rowvals(p1, wy0 - 3, b0a); rowvals(p2, wy0 - 3, b0b);
    rowvals(p1, wy0 - 2, b1a); rowvals(p2, wy0 - 2, b1b);
    rowvals(p1, wy0 - 1, b2a); rowvals(p2, wy0 - 1, b2b);
    rowvals(p1, wy0 + 0, b3a); rowvals(p2, wy0 + 0, b3b);
    rowvals(p1, wy0 + 1, b4a); rowvals(p2, wy0 + 1, b4b);
    rowvals(p1, wy0 + 2, b5a); rowvals(p2, wy0 + 2, b5b);
    rowvals(p1, wy0 + 3, b6a); rowvals(p2, wy0 + 3, b6b);
    rowvals(p1, wy0 + 4, b7a); rowvals(p2, wy0 + 4, b7b);

    float s1[8], s2[8], s11[8], s22[8], s12[8];
    #pragma unroll
    for (int k = 0; k < 8; ++k) { s1[k] = s2[k] = s11[k] = s22[k] = s12[k] = 0.f; }

    accrow(b0a, b0b, s1, s2, s11, s22, s12);   // +q0
    accrow(b1a, b1b, s1, s2, s11, s22, s12);   // +q1
    accrow(b2a, b2b, s1, s2, s11, s22, s12);   // +q2
    accrow(b3a, b3b, s1, s2, s11, s22, s12);   // +q3
    accrow(b4a, b4b, s1, s2, s11, s22, s12);   // +q4
    accrow(b5a, b5b, s1, s2, s11, s22, s12);   // +q5
    accrow(b6a, b6b, s1, s2, s11, s22, s12);   // +q6  (window q0..q6)

    float acc = rowssim(s1, s2, s11, s22, s12);           // row wy0

    subrow(b0a, b0b, s1, s2, s11, s22, s12);   // -q0
    accrow(b7a, b7b, s1, s2, s11, s22, s12);   // +q7  (window q1..q7)

    acc += rowssim(s1, s2, s11, s22, s12);                // row wy0+1

    // block reduction: wave shuffle-reduce then LDS across 4 waves
    #pragma unroll
    for (int off = 32; off; off >>= 1) acc += __shfl_down(acc, off, 64);

    __shared__ float red[NWAVE];
    if (lane == 0) red[wv] = acc;
    __syncthreads();
    if (tid == 0) {
        partials[bid] = (red[0] + red[1]) + (red[2] + red[3]);
    }
}

extern "C" __global__ void __launch_bounds__(256)
ssim_final(const float* __restrict__ partials, float* __restrict__ out)
{
    // 256 threads, 8 serial loads each, fixed order -> deterministic
    const int tid  = threadIdx.x;
    const int lane = tid & 63;
    const int wv   = tid >> 6;
    double s = 0.0;
    #pragma unroll
    for (int i = 0; i < NBLK / 256; ++i) s += (double)partials[tid + (i << 8)];
    #pragma unroll
    for (int off = 32; off; off >>= 1) s += __shfl_down(s, off, 64);
    __shared__ double sd[4];
    if (lane == 0) sd[wv] = s;
    __syncthreads();
    if (tid == 0) {
        const double t = (sd[0] + sd[1]) + (sd[2] + sd[3]);
        out[0] = (float)(1.0 - t / ((double)NIMG * IMG_H * IMG_W));
    }
}

extern "C" void kernel_launch(void* const* d_in, const int* in_sizes, int n_in,
                              void* d_out, int out_size, void* d_ws, size_t ws_size,
                              hipStream_t stream) {
    const float* img1 = (const float*)d_in[0];
    const float* img2 = (const float*)d_in[1];
    float* partials = (float*)d_ws;   // NBLK floats

    hipLaunchKernelGGL(ssim_main, dim3(NBLK), dim3(256), 0, stream,
                       img1, img2, partials);
    hipLaunchKernelGGL(ssim_final, dim3(1), dim3(256), 0, stream,
                       partials, (float*)d_out);
}